// Round 12
// baseline (1074.091 us; speedup 1.0000x reference)
//
#include <hip/hip_runtime.h>

#define NTOK  49
#define NWIN  1024
#define SCALE 0.17677669529663687f

// LDS (static, 124 KB -> 1 block/CU):
//  xb  @0       : [64][400B] x bf16 (pad rows 49..63 zeroed once)
//  qb  @25600   : [4 tt][6 h][64 lane][16B] = 24576
//  kb  @50176   : [4 tt][6 h][64 lane][16B] = 24576
//  vt  @74752   : [192 ch][144 B] = 27648
//  obx @102400  : [qt][H][64 lane][16B] = 24576   (separate: xb stays live)
#define SMEM_BYTES 126976

typedef __bf16 bfx8 __attribute__((ext_vector_type(8)));
typedef float  f32x4 __attribute__((ext_vector_type(4)));
typedef unsigned long long ull;
typedef unsigned int uint;

union BF8 { bfx8 v; ull q[2]; };

__device__ __forceinline__ unsigned short f2bf(float f) {
    uint u = __builtin_bit_cast(uint, f);
    u += 0x7fffu + ((u >> 16) & 1u);
    return (unsigned short)(u >> 16);
}
__device__ __forceinline__ float bf2f(uint u16) {
    uint x = (u16 & 0xffffu) << 16;
    return __builtin_bit_cast(float, x);
}
__device__ __forceinline__ ull pack4(f32x4 a) {
    return (ull)f2bf(a[0]) | ((ull)f2bf(a[1]) << 16) |
           ((ull)f2bf(a[2]) << 32) | ((ull)f2bf(a[3]) << 48);
}

// W1f[oct 0..35][kk 0..5][lane][8]: lane(g,jn) holds qkv_w[oct*16+jn][kk*32+g*8 ..+8]
// W2p[c2t*6+H][lane][8]: e<4 -> proj_w[c2t*16+jn][H*32+4g+e]; e>=4 -> [.. +16+4g+(e-4)]
// biasB[h][i][j pad 68] bf16: j<49 -> rpb[rel[i*49+j]*6+h], else -1e30 (softmax mask)
extern "C" __global__ void wattn_prep(const float* __restrict__ qkv_w,
                                      const float* __restrict__ proj_w,
                                      const float* __restrict__ rpb,
                                      const int*   __restrict__ rel,
                                      const float* __restrict__ qkv_b,
                                      unsigned short* __restrict__ W1f,
                                      unsigned short* __restrict__ W2p,
                                      float* __restrict__ qkvbs,
                                      unsigned short* __restrict__ biasB)
{
    const int i = blockIdx.x * 256 + threadIdx.x;
    if (i < 110592) {
        const int e = i & 7, l = (i >> 3) & 63, f = i >> 9;
        const int kk = f % 6, oct = f / 6;
        const int R = oct * 16 + (l & 15), C = kk * 32 + (l >> 4) * 8 + e;
        float v = qkv_w[R * 192 + C];
        if (oct < 12) v *= SCALE;
        W1f[i] = f2bf(v);
    }
    if (i < 36864) {
        const int e = i & 7, l = (i >> 3) & 63, f = i >> 9;
        const int c2t = f / 6, H = f % 6;
        const int R = c2t * 16 + (l & 15);
        const int C = H * 32 + (e >> 2) * 16 + (l >> 4) * 4 + (e & 3);
        W2p[i] = f2bf(proj_w[R * 192 + C]);
    }
    if (i < 576) qkvbs[i] = (i < 192) ? qkv_b[i] * SCALE : qkv_b[i];
    if (i < 6 * NTOK * 68) {                 // biasB[h][i][j], j padded to 68
        const int h = i / (NTOK * 68), ii = (i / 68) % NTOK, j = i % 68;
        biasB[i] = (j < NTOK) ? f2bf(rpb[rel[ii * NTOK + j] * 6 + h]) : f2bf(-1e30f);
    }
}

extern "C" __global__ void __launch_bounds__(512, 2)
wattn_fused(const float* __restrict__ x,
            const float* __restrict__ mask,
            const float* __restrict__ proj_b,
            const unsigned short* __restrict__ W1f,
            const unsigned short* __restrict__ W2p,
            const float* __restrict__ qkvbs,
            const unsigned short* __restrict__ biasB,
            float* __restrict__ out)
{
    __shared__ char smem[SMEM_BYTES];
    char* const XB  = smem;
    char* const QBp = smem + 25600;
    char* const KBp = smem + 50176;
    char* const VTp = smem + 74752;
    char* const OBX = smem + 102400;

    const int tid  = threadIdx.x;
    const int wave = tid >> 6;
    const int lane = tid & 63;
    const int g    = lane >> 4;
    const int jn   = lane & 15;
    const int qt   = wave & 3;
    const int hh   = wave >> 2;
    const size_t b2 = (size_t)blockIdx.x * 2;

    // ---- prefetch first qkv weight job (oct = wave) ----
    bfx8 wfp[6];
#pragma unroll
    for (int kk = 0; kk < 6; ++kk)
        wfp[kk] = *(const bfx8*)(W1f + ((size_t)(wave * 6 + kk) * 64 + lane) * 8);

    // ---- zero x pad rows (once; both windows reuse), stage x(w0) ----
#pragma unroll
    for (int u = 0; u < 3; ++u) {
        const int i = tid + u * 512;
        if (i < 1500)
            *(uint*)(XB + (49 + i / 100) * 400 + (i % 100) * 4) = 0u;
    }
    {
        const float4* xw = (const float4*)(x + b2 * 9408);
#pragma unroll
        for (int u = 0; u < 5; ++u) {
            const int i = tid + u * 512;
            if (i < 2352) {
                float4 v = xw[i];
                *(ull*)(XB + (i / 48) * 400 + (i % 48) * 8) =
                    (ull)f2bf(v.x) | ((ull)f2bf(v.y) << 16) |
                    ((ull)f2bf(v.z) << 32) | ((ull)f2bf(v.w) << 48);
            }
        }
    }
    __syncthreads();                                              // B1

    for (int w = 0; w < 2; ++w) {
        // ---- qkv: 4 full octs per wave + 1 shared half-oct ----
#pragma unroll
        for (int jj = 0; jj < 4; ++jj) {
            const int oct = wave + 8 * jj;                // 0..31
            bfx8 wf_[6];
#pragma unroll
            for (int kk = 0; kk < 6; ++kk)
                wf_[kk] = (jj == 0) ? wfp[kk]
                        : *(const bfx8*)(W1f + ((size_t)(oct * 6 + kk) * 64 + lane) * 8);
            if (oct < 24) {                               // Q or K: swapped mfma(w, x)
                const f32x4 binit = *(const f32x4*)(qkvbs + oct * 16 + 4 * g);
                char* const dst = (oct < 12) ? QBp : KBp;
                const int ct12 = (oct < 12) ? oct : oct - 12;
#pragma unroll
                for (int tt = 0; tt < 4; ++tt) {
                    f32x4 acc = binit;
#pragma unroll
                    for (int kk = 0; kk < 6; ++kk) {
                        bfx8 xf = *(const bfx8*)(XB + (tt * 16 + jn) * 400 + kk * 64 + g * 16);
                        acc = __builtin_amdgcn_mfma_f32_16x16x32_bf16(wf_[kk], xf, acc, 0, 0, 0);
                    }
                    *(ull*)(dst + ((tt * 6 + (ct12 >> 1)) * 64 + lane) * 16 + (ct12 & 1) * 8) = pack4(acc);
                }
            } else {                                      // V: unswapped mfma(x, w)
                const float bv = qkvbs[oct * 16 + jn];
                const int ct12 = oct - 24;
#pragma unroll
                for (int tt = 0; tt < 4; ++tt) {
                    f32x4 acc = {bv, bv, bv, bv};
#pragma unroll
                    for (int kk = 0; kk < 6; ++kk) {
                        bfx8 xf = *(const bfx8*)(XB + (tt * 16 + jn) * 400 + kk * 64 + g * 16);
                        acc = __builtin_amdgcn_mfma_f32_16x16x32_bf16(xf, wf_[kk], acc, 0, 0, 0);
                    }
                    *(ull*)(VTp + (ct12 * 16 + jn) * 144 + (tt >> 1) * 64 + g * 16 + (tt & 1) * 8) = pack4(acc);
                }
            }
        }
        {   // shared half-oct: octs 32..35 (V), split across wave pairs by tt
            const int oct = 32 + (wave >> 1);
            const int ct12 = oct - 24;
            const int ttb = (wave & 1) * 2;
            bfx8 wf_[6];
#pragma unroll
            for (int kk = 0; kk < 6; ++kk)
                wf_[kk] = *(const bfx8*)(W1f + ((size_t)(oct * 6 + kk) * 64 + lane) * 8);
            const float bv = qkvbs[oct * 16 + jn];
#pragma unroll
            for (int t2 = 0; t2 < 2; ++t2) {
                const int tt = ttb + t2;
                f32x4 acc = {bv, bv, bv, bv};
#pragma unroll
                for (int kk = 0; kk < 6; ++kk) {
                    bfx8 xf = *(const bfx8*)(XB + (tt * 16 + jn) * 400 + kk * 64 + g * 16);
                    acc = __builtin_amdgcn_mfma_f32_16x16x32_bf16(xf, wf_[kk], acc, 0, 0, 0);
                }
                *(ull*)(VTp + (ct12 * 16 + jn) * 144 + (tt >> 1) * 64 + g * 16 + (tt & 1) * 8) = pack4(acc);
            }
        }
        __syncthreads();                                          // B2

        // ---- attention: wave (qt,hh) does 3 heads ----
        const int iq = qt * 16 + jn;
        const int ic = iq < NTOK ? iq : NTOK - 1;
        const float* mw = mask + ((b2 + w) & (NWIN - 1)) * (NTOK * NTOK);
        float mv[4][4];
#pragma unroll
        for (int kt = 0; kt < 4; ++kt)
#pragma unroll
            for (int r = 0; r < 4; ++r) {
                const int j = kt * 16 + 4 * g + r;
                const int jc = j < NTOK ? j : NTOK - 1;
                mv[kt][r] = mw[ic * NTOK + jc];      // mask[i][j]
            }

#pragma unroll
        for (int hl = 0; hl < 3; ++hl) {
            const int H = hh * 3 + hl;
            bfx8 qfr = *(const bfx8*)(QBp + ((qt * 6 + H) * 64 + lane) * 16);
            f32x4 p[4];
#pragma unroll
            for (int kt = 0; kt < 4; ++kt) {
                bfx8 kf = *(const bfx8*)(KBp + ((kt * 6 + H) * 64 + lane) * 16);
                f32x4 z = {0.f, 0.f, 0.f, 0.f};
                p[kt] = __builtin_amdgcn_mfma_f32_16x16x32_bf16(kf, qfr, z, 0, 0, 0);
            }
            float mx = -1e30f;
#pragma unroll
            for (int kt = 0; kt < 4; ++kt) {
                const ull bq = *(const ull*)(biasB + (size_t)(H * NTOK + ic) * 68 + kt * 16 + 4 * g);
#pragma unroll
                for (int r = 0; r < 4; ++r) {
                    // bias pad (j>=49) = -1e30 masks the tail; no select needed
                    const float v = p[kt][r] + bf2f((uint)(bq >> (16 * r))) + mv[kt][r];
                    p[kt][r] = v;
                    mx = fmaxf(mx, v);
                }
            }
            mx = fmaxf(mx, __shfl_xor(mx, 16));
            mx = fmaxf(mx, __shfl_xor(mx, 32));
            float sum = 0.f;
#pragma unroll
            for (int kt = 0; kt < 4; ++kt)
#pragma unroll
                for (int r = 0; r < 4; ++r) {
                    p[kt][r] = __expf(p[kt][r] - mx);
                    sum += p[kt][r];
                }
            sum += __shfl_xor(sum, 16);
            sum += __shfl_xor(sum, 32);
            const float inv = 1.f / sum;
            BF8 p01, p23;
            p01.q[0] = pack4(p[0]); p01.q[1] = pack4(p[1]);
            p23.q[0] = pack4(p[2]); p23.q[1] = pack4(p[3]);
#pragma unroll
            for (int ct = 0; ct < 2; ++ct) {
                const int row = H * 32 + ct * 16 + jn;
                bfx8 v0 = *(const bfx8*)(VTp + row * 144 + g * 16);
                bfx8 v1 = *(const bfx8*)(VTp + row * 144 + 64 + g * 16);
                f32x4 o = {0.f, 0.f, 0.f, 0.f};
                o = __builtin_amdgcn_mfma_f32_16x16x32_bf16(v0, p01.v, o, 0, 0, 0);
                o = __builtin_amdgcn_mfma_f32_16x16x32_bf16(v1, p23.v, o, 0, 0, 0);
                *(ull*)(OBX + ((qt * 6 + H) * 64 + lane) * 16 + ct * 8) = pack4(o * inv);
            }
        }

        // ---- prefetch first proj weight job, then barrier ----
        bfx8 wf2p[6];
#pragma unroll
        for (int H = 0; H < 6; ++H)
            wf2p[H] = *(const bfx8*)(W2p + ((size_t)((wave >> 1) * 6 + H) * 64 + lane) * 8);
        __syncthreads();                                          // B3

        // ---- proj (+ for w==0: overlap next window's x stage) ----
        float4 xr[5];
        if (w == 0) {                 // issue next-window x loads early
            const float4* xw1 = (const float4*)(x + (b2 + 1) * 9408);
#pragma unroll
            for (int u = 0; u < 5; ++u) {
                const int i = tid + u * 512;
                xr[u] = (i < 2352) ? xw1[i] : (float4){0.f, 0.f, 0.f, 0.f};
            }
        }
        float* outp = out + (b2 + w) * 9408;
#pragma unroll
        for (int t = 0; t < 3; ++t) {
            const int j = wave + 8 * t;
            const int c2t = j >> 1;
            const int qh  = j & 1;
            bfx8 wf2[6];
#pragma unroll
            for (int H = 0; H < 6; ++H)
                wf2[H] = (t == 0) ? wf2p[H]
                       : *(const bfx8*)(W2p + ((size_t)(c2t * 6 + H) * 64 + lane) * 8);
            const f32x4 pb = *(const f32x4*)(proj_b + c2t * 16 + 4 * g);
#pragma unroll
            for (int t2 = 0; t2 < 2; ++t2) {
                const int qt2 = qh * 2 + t2;
                f32x4 acc = pb;
#pragma unroll
                for (int H = 0; H < 6; ++H) {
                    bfx8 ob = *(const bfx8*)(OBX + ((qt2 * 6 + H) * 64 + lane) * 16);
                    acc = __builtin_amdgcn_mfma_f32_16x16x32_bf16(wf2[H], ob, acc, 0, 0, 0);
                }
                const int tok = qt2 * 16 + jn;
                if (tok < NTOK)
                    *(f32x4*)(outp + tok * 192 + c2t * 16 + 4 * g) = acc;
            }
        }
        if (w == 0) {                 // write next window's x into xb, refill wfp
#pragma unroll
            for (int u = 0; u < 5; ++u) {
                const int i = tid + u * 512;
                if (i < 2352) {
                    float4 v = xr[u];
                    *(ull*)(XB + (i / 48) * 400 + (i % 48) * 8) =
                        (ull)f2bf(v.x) | ((ull)f2bf(v.y) << 16) |
                        ((ull)f2bf(v.z) << 32) | ((ull)f2bf(v.w) << 48);
                }
            }
#pragma unroll
            for (int kk = 0; kk < 6; ++kk)
                wfp[kk] = *(const bfx8*)(W1f + ((size_t)(wave * 6 + kk) * 64 + lane) * 8);
            __syncthreads();                                      // B4
        }
    }
}

extern "C" void kernel_launch(void* const* d_in, const int* in_sizes, int n_in,
                              void* d_out, int out_size, void* d_ws, size_t ws_size,
                              hipStream_t stream) {
    const float* x      = (const float*)d_in[0];
    const float* mask   = (const float*)d_in[1];
    const float* qkv_w  = (const float*)d_in[2];
    const float* qkv_b  = (const float*)d_in[3];
    const float* proj_w = (const float*)d_in[4];
    const float* proj_b = (const float*)d_in[5];
    const float* rpb    = (const float*)d_in[6];
    const int*   rel    = (const int*)d_in[7];
    float* outp = (float*)d_out;

    char* ws = (char*)d_ws;
    unsigned short* W1f   = (unsigned short*)ws;                   // 221184 B
    unsigned short* W2p   = (unsigned short*)(ws + 221184);        //  73728 B
    float* qkvbs          = (float*)(ws + 221184 + 73728);         //   2304 B
    unsigned short* biasB = (unsigned short*)(ws + 221184 + 73728 + 2304); // 39984 B

    wattn_prep<<<432, 256, 0, stream>>>(qkv_w, proj_w, rpb, rel, qkv_b,
                                        W1f, W2p, qkvbs, biasB);
    wattn_fused<<<4096, 512, 0, stream>>>(x, mask, proj_b,
                                          W1f, W2p, qkvbs, biasB, outp);
}

// Round 13
// 431.553 us; speedup vs baseline: 2.4889x; 2.4889x over previous
//
#include <hip/hip_runtime.h>

#define NTOK  49
#define NWIN  1024
#define SCALE 0.17677669529663687f

// LDS (static, 102.4 KB -> 1 block/CU):
//  xb  @0      : [64][400B] x bf16               -- dead after qkv phase
//  obx @0      : [qt][H][64 lane][16B] = 24576   -- aliases xb, written in attn
//  qb  @25600  : [4 tt][6 h][64 lane][16B] = 24576
//  kb  @50176  : [4 tt][6 h][64 lane][16B] = 24576
//  vt  @74752  : [192 ch][144 B] = 27648
#define SMEM_BYTES 102400

typedef __bf16 bfx8 __attribute__((ext_vector_type(8)));
typedef float  f32x4 __attribute__((ext_vector_type(4)));
typedef unsigned long long ull;
typedef unsigned int uint;

union BF8 { bfx8 v; ull q[2]; };

__device__ __forceinline__ unsigned short f2bf(float f) {
    uint u = __builtin_bit_cast(uint, f);
    u += 0x7fffu + ((u >> 16) & 1u);
    return (unsigned short)(u >> 16);
}
__device__ __forceinline__ ull pack4(f32x4 a) {
    return (ull)f2bf(a[0]) | ((ull)f2bf(a[1]) << 16) |
           ((ull)f2bf(a[2]) << 32) | ((ull)f2bf(a[3]) << 48);
}
__device__ __forceinline__ f32x4 mfma16(bfx8 a, bfx8 b, f32x4 c) {
    return __builtin_amdgcn_mfma_f32_16x16x32_bf16(a, b, c, 0, 0, 0);
}

// W1f[oct 0..35][kk 0..5][lane][8]: lane(g,jn) holds qkv_w[oct*16+jn][kk*32+g*8 ..+8]
// W2p[c2t*6+H][lane][8]: e<4 -> proj_w[c2t*16+jn][H*32+4g+e]; e>=4 -> [.. +16+4g+(e-4)]
// biasN[h][i][j pad 64] f32: j<49 -> rpb[rel[i*49+j]*6+h], else -1e30 (tail mask)
extern "C" __global__ void wattn_prep(const float* __restrict__ qkv_w,
                                      const float* __restrict__ proj_w,
                                      const float* __restrict__ rpb,
                                      const int*   __restrict__ rel,
                                      const float* __restrict__ qkv_b,
                                      unsigned short* __restrict__ W1f,
                                      unsigned short* __restrict__ W2p,
                                      float* __restrict__ qkvbs,
                                      float* __restrict__ biasN)
{
    const int i = blockIdx.x * 256 + threadIdx.x;
    if (i < 110592) {
        const int e = i & 7, l = (i >> 3) & 63, f = i >> 9;
        const int kk = f % 6, oct = f / 6;
        const int R = oct * 16 + (l & 15), C = kk * 32 + (l >> 4) * 8 + e;
        float v = qkv_w[R * 192 + C];
        if (oct < 12) v *= SCALE;
        W1f[i] = f2bf(v);
    }
    if (i < 36864) {
        const int e = i & 7, l = (i >> 3) & 63, f = i >> 9;
        const int c2t = f / 6, H = f % 6;
        const int R = c2t * 16 + (l & 15);
        const int C = H * 32 + (e >> 2) * 16 + (l >> 4) * 4 + (e & 3);
        W2p[i] = f2bf(proj_w[R * 192 + C]);
    }
    if (i < 576) qkvbs[i] = (i < 192) ? qkv_b[i] * SCALE : qkv_b[i];
    if (i < 6 * NTOK * 64) {                 // biasN[h][i][j], j padded to 64
        const int h = i / (NTOK * 64), ii = (i / 64) % NTOK, j = i % 64;
        biasN[i] = (j < NTOK) ? rpb[rel[ii * NTOK + j] * 6 + h] : -1e30f;
    }
}

extern "C" __global__ void __launch_bounds__(512, 2)
wattn_fused(const float* __restrict__ x,
            const float* __restrict__ mask,
            const float* __restrict__ proj_b,
            const unsigned short* __restrict__ W1f,
            const unsigned short* __restrict__ W2p,
            const float* __restrict__ qkvbs,
            const float* __restrict__ biasN,
            float* __restrict__ out)
{
    __shared__ char smem[SMEM_BYTES];
    char* const XB  = smem;
    char* const OBX = smem;
    char* const QBp = smem + 25600;
    char* const KBp = smem + 50176;
    char* const VTp = smem + 74752;

    const int tid  = threadIdx.x;
    const int wave = tid >> 6;
    const int lane = tid & 63;
    const int g    = lane >> 4;
    const int jn   = lane & 15;
    const int qt   = wave & 3;
    const int hh   = wave >> 2;
    const size_t b = blockIdx.x;

    // ---- stage x -> bf16 LDS, zero pad rows 49..63 ----
#pragma unroll
    for (int u = 0; u < 3; ++u) {
        const int i = tid + u * 512;
        if (i < 1500)
            *(uint*)(XB + (49 + i / 100) * 400 + (i % 100) * 4) = 0u;
    }
    {
        const float4* xw = (const float4*)(x + b * 9408);
#pragma unroll
        for (int u = 0; u < 5; ++u) {
            const int i = tid + u * 512;
            if (i < 2352) {
                float4 v = xw[i];
                *(ull*)(XB + (i / 48) * 400 + (i % 48) * 8) =
                    (ull)f2bf(v.x) | ((ull)f2bf(v.y) << 16) |
                    ((ull)f2bf(v.z) << 32) | ((ull)f2bf(v.w) << 48);
            }
        }
    }
    __syncthreads();                                              // B1

    // ---- qkv: 16 oct-pairs over 8 waves (2 each); one xf stream feeds 2 octs ----
#pragma unroll
    for (int jj = 0; jj < 2; ++jj) {
        const int pr = wave + 8 * jj;            // 0..15
        const int octA = pr * 2;
        bfx8 wfA[6], wfB[6];
#pragma unroll
        for (int kk = 0; kk < 6; ++kk) {
            wfA[kk] = *(const bfx8*)(W1f + ((size_t)(octA * 6 + kk) * 64 + lane) * 8);
            wfB[kk] = *(const bfx8*)(W1f + ((size_t)((octA + 1) * 6 + kk) * 64 + lane) * 8);
        }
        if (pr < 12) {                            // Q (pr<6) or K: swapped mfma(w,x)
            const f32x4 biA = *(const f32x4*)(qkvbs + octA * 16 + 4 * g);
            const f32x4 biB = *(const f32x4*)(qkvbs + (octA + 1) * 16 + 4 * g);
            char* const dst = (pr < 6) ? QBp : KBp;
            const int pp = (pr < 6) ? pr : pr - 6;
#pragma unroll
            for (int tt = 0; tt < 4; ++tt) {
                f32x4 aA = biA, aB = biB;
#pragma unroll
                for (int kk = 0; kk < 6; ++kk) {
                    bfx8 xf = *(const bfx8*)(XB + (tt * 16 + jn) * 400 + kk * 64 + g * 16);
                    aA = mfma16(wfA[kk], xf, aA);
                    aB = mfma16(wfB[kk], xf, aB);
                }
                BF8 o; o.q[0] = pack4(aA); o.q[1] = pack4(aB);
                *(bfx8*)(dst + ((tt * 6 + pp) * 64 + lane) * 16) = o.v;
            }
        } else {                                  // V pair: unswapped mfma(x,w)
            const float bvA = qkvbs[octA * 16 + jn];
            const float bvB = qkvbs[(octA + 1) * 16 + jn];
            const int cA = octA - 24;             // 0,2,4,6
#pragma unroll
            for (int tt = 0; tt < 4; ++tt) {
                f32x4 aA = {bvA, bvA, bvA, bvA};
                f32x4 aB = {bvB, bvB, bvB, bvB};
#pragma unroll
                for (int kk = 0; kk < 6; ++kk) {
                    bfx8 xf = *(const bfx8*)(XB + (tt * 16 + jn) * 400 + kk * 64 + g * 16);
                    aA = mfma16(xf, wfA[kk], aA);
                    aB = mfma16(xf, wfB[kk], aB);
                }
                const int voff = (tt >> 1) * 64 + g * 16 + (tt & 1) * 8;
                *(ull*)(VTp + (cA * 16 + jn) * 144 + voff)       = pack4(aA);
                *(ull*)(VTp + ((cA + 1) * 16 + jn) * 144 + voff) = pack4(aB);
            }
        }
        __builtin_amdgcn_sched_barrier(0);
    }
    {   // tail: V octs 32..35 (pairs 16,17); wave w: pair 16+(w>>2), tt=w&3
        const int octA = 32 + (wave >> 2) * 2;
        const int tt = wave & 3;
        bfx8 wfA[6], wfB[6];
#pragma unroll
        for (int kk = 0; kk < 6; ++kk) {
            wfA[kk] = *(const bfx8*)(W1f + ((size_t)(octA * 6 + kk) * 64 + lane) * 8);
            wfB[kk] = *(const bfx8*)(W1f + ((size_t)((octA + 1) * 6 + kk) * 64 + lane) * 8);
        }
        const float bvA = qkvbs[octA * 16 + jn];
        const float bvB = qkvbs[(octA + 1) * 16 + jn];
        f32x4 aA = {bvA, bvA, bvA, bvA};
        f32x4 aB = {bvB, bvB, bvB, bvB};
#pragma unroll
        for (int kk = 0; kk < 6; ++kk) {
            bfx8 xf = *(const bfx8*)(XB + (tt * 16 + jn) * 400 + kk * 64 + g * 16);
            aA = mfma16(xf, wfA[kk], aA);
            aB = mfma16(xf, wfB[kk], aB);
        }
        const int cA = octA - 24;                 // 8,10
        const int voff = (tt >> 1) * 64 + g * 16 + (tt & 1) * 8;
        *(ull*)(VTp + (cA * 16 + jn) * 144 + voff)       = pack4(aA);
        *(ull*)(VTp + ((cA + 1) * 16 + jn) * 144 + voff) = pack4(aB);
    }
    __syncthreads();                                              // B2

    // ---- attention: wave (qt,hh) does 3 heads; bias pad -1e30 masks tail ----
    const int iq = qt * 16 + jn;
    const int ic = iq < NTOK ? iq : NTOK - 1;
    const float* mw = mask + (b & (NWIN - 1)) * (NTOK * NTOK);
    float mv[4][4];
#pragma unroll
    for (int kt = 0; kt < 4; ++kt)
#pragma unroll
        for (int r = 0; r < 4; ++r) {
            const int j = kt * 16 + 4 * g + r;
            const int jc = j < NTOK ? j : NTOK - 1;
            mv[kt][r] = mw[ic * NTOK + jc];      // mask[i][j]
        }

#pragma unroll
    for (int hl = 0; hl < 3; ++hl) {
        const int H = hh * 3 + hl;
        bfx8 qfr = *(const bfx8*)(QBp + ((qt * 6 + H) * 64 + lane) * 16);
        f32x4 p[4];
#pragma unroll
        for (int kt = 0; kt < 4; ++kt) {
            bfx8 kf = *(const bfx8*)(KBp + ((kt * 6 + H) * 64 + lane) * 16);
            f32x4 z = {0.f, 0.f, 0.f, 0.f};
            p[kt] = mfma16(kf, qfr, z);
        }
        float mx = -1e30f;
#pragma unroll
        for (int kt = 0; kt < 4; ++kt) {
            const f32x4 bm4 = *(const f32x4*)(biasN + ((size_t)H * NTOK + ic) * 64 + kt * 16 + 4 * g);
#pragma unroll
            for (int r = 0; r < 4; ++r) {
                // j>=49 entries carry bias=-1e30 -> exp underflows to 0; no select
                const float v = p[kt][r] + bm4[r] + mv[kt][r];
                p[kt][r] = v;
                mx = fmaxf(mx, v);
            }
        }
        mx = fmaxf(mx, __shfl_xor(mx, 16));
        mx = fmaxf(mx, __shfl_xor(mx, 32));
        float sum = 0.f;
#pragma unroll
        for (int kt = 0; kt < 4; ++kt)
#pragma unroll
            for (int r = 0; r < 4; ++r) {
                p[kt][r] = __expf(p[kt][r] - mx);
                sum += p[kt][r];
            }
        sum += __shfl_xor(sum, 16);
        sum += __shfl_xor(sum, 32);
        const float inv = 1.f / sum;
        BF8 p01, p23;
        p01.q[0] = pack4(p[0]); p01.q[1] = pack4(p[1]);
        p23.q[0] = pack4(p[2]); p23.q[1] = pack4(p[3]);
#pragma unroll
        for (int ct = 0; ct < 2; ++ct) {
            const int row = H * 32 + ct * 16 + jn;
            bfx8 v0 = *(const bfx8*)(VTp + row * 144 + g * 16);
            bfx8 v1 = *(const bfx8*)(VTp + row * 144 + 64 + g * 16);
            f32x4 o = {0.f, 0.f, 0.f, 0.f};
            o = mfma16(v0, p01.v, o);
            o = mfma16(v1, p23.v, o);
            *(ull*)(OBX + ((qt * 6 + H) * 64 + lane) * 16 + ct * 8) = pack4(o * inv);
        }
    }
    __syncthreads();                                              // B3

    // ---- proj: 24 balanced jobs (c2t x token-half), 3 per wave ----
    float* outp = out + b * 9408;
#pragma unroll
    for (int t = 0; t < 3; ++t) {
        const int j = wave + 8 * t;
        const int c2t = j >> 1;
        const int qh  = j & 1;
        bfx8 wf2[6];
#pragma unroll
        for (int H = 0; H < 6; ++H)
            wf2[H] = *(const bfx8*)(W2p + ((size_t)(c2t * 6 + H) * 64 + lane) * 8);
        const f32x4 pb = *(const f32x4*)(proj_b + c2t * 16 + 4 * g);
#pragma unroll
        for (int t2 = 0; t2 < 2; ++t2) {
            const int qt2 = qh * 2 + t2;
            f32x4 acc = pb;
#pragma unroll
            for (int H = 0; H < 6; ++H) {
                bfx8 ob = *(const bfx8*)(OBX + ((qt2 * 6 + H) * 64 + lane) * 16);
                acc = mfma16(wf2[H], ob, acc);
            }
            const int tok = qt2 * 16 + jn;
            if (tok < NTOK)
                *(f32x4*)(outp + tok * 192 + c2t * 16 + 4 * g) = acc;
        }
    }
}

extern "C" void kernel_launch(void* const* d_in, const int* in_sizes, int n_in,
                              void* d_out, int out_size, void* d_ws, size_t ws_size,
                              hipStream_t stream) {
    const float* x      = (const float*)d_in[0];
    const float* mask   = (const float*)d_in[1];
    const float* qkv_w  = (const float*)d_in[2];
    const float* qkv_b  = (const float*)d_in[3];
    const float* proj_w = (const float*)d_in[4];
    const float* proj_b = (const float*)d_in[5];
    const float* rpb    = (const float*)d_in[6];
    const int*   rel    = (const int*)d_in[7];
    float* outp = (float*)d_out;

    char* ws = (char*)d_ws;
    unsigned short* W1f = (unsigned short*)ws;                     // 221184 B
    unsigned short* W2p = (unsigned short*)(ws + 221184);          //  73728 B
    float* qkvbs        = (float*)(ws + 221184 + 73728);           //   2304 B
    float* biasN        = (float*)(ws + 221184 + 73728 + 2304);    //  75264 B

    wattn_prep<<<432, 256, 0, stream>>>(qkv_w, proj_w, rpb, rel, qkv_b,
                                        W1f, W2p, qkvbs, biasN);
    wattn_fused<<<8192, 512, 0, stream>>>(x, mask, proj_b,
                                          W1f, W2p, qkvbs, biasN, outp);
}